// Round 1
// baseline (127.717 us; speedup 1.0000x reference)
//
#include <hip/hip_runtime.h>
#include <math.h>

#define EMBED 256
#define HEADS 8
#define PDIM  32
#define BATCH 2
#define SEQ   1728            // 12*12*12
#define NTOK  (BATCH*SEQ)     // 3456
#define NE    (NTOK*EMBED)    // 884736
#define NKT   (SEQ/64)        // 27 key tiles
#define NPAIR ((NKT+1)/2)     // 14 paired tile iterations
#define WSZ   (EMBED*EMBED)   // 65536
#define XCH   (NE/8)          // 110592 x-chunks
#define WCH   (WSZ/8)         // 8192 W-chunks
#define LOG2E 1.44269504088896f

typedef __attribute__((ext_vector_type(8))) __bf16 bf16x8;
typedef __attribute__((ext_vector_type(4))) float  f32x4;
typedef unsigned short ushort_t;
typedef unsigned int   uint_t;

static __device__ __forceinline__ unsigned short f2bf_rne(float f) {
    union { float f; unsigned u; } x; x.f = f;
    unsigned r = x.u + 0x7fffu + ((x.u >> 16) & 1u);
    return (unsigned short)(r >> 16);
}
union v8cast { uint4 u; bf16x8 v; };

// split 8 floats into bf16 hi (round-half-up) + bf16 lo residual, packed
static __device__ __forceinline__ void cvt8_hilo(const float f[8], bf16x8& hi, bf16x8& lo) {
    uint4 ph, pl;
    uint_t* phv = (uint_t*)&ph; uint_t* plv = (uint_t*)&pl;
    #pragma unroll
    for (int j = 0; j < 4; ++j) {
        const float f0 = f[2 * j], f1 = f[2 * j + 1];
        const uint_t u0 = __float_as_uint(f0) + 0x8000u;
        const uint_t u1 = __float_as_uint(f1) + 0x8000u;
        phv[j] = __builtin_amdgcn_perm(u1, u0, 0x07060302u);
        const float l0 = f0 - __uint_as_float(u0 & 0xFFFF0000u);
        const float l1 = f1 - __uint_as_float(u1 & 0xFFFF0000u);
        plv[j] = __builtin_amdgcn_perm(__float_as_uint(l1) + 0x8000u,
                                       __float_as_uint(l0) + 0x8000u, 0x07060302u);
    }
    v8cast ch; ch.u = ph; hi = ch.v;
    v8cast cl; cl.u = pl; lo = cl.v;
}

// ---------------------------------------------------------------------------
// Kernel 0: one-time conversions (bit-identical rounding to old in-kernel cvt):
//   x  -> xhi,xlo  bf16 [NTOK][E]
//   Wq/Wk/Wv -> TRANSPOSED hi/lo bf16 [z][n][k]
//   Wo -> TRANSPOSED hi bf16 [n][k]
// grid 560 x 256.
// ---------------------------------------------------------------------------
__global__ __launch_bounds__(256) void prep_kernel(
    const float* __restrict__ x,
    const float* __restrict__ Wq, const float* __restrict__ Wk,
    const float* __restrict__ Wv, const float* __restrict__ Wo,
    ushort_t* __restrict__ xhi, ushort_t* __restrict__ xlo,
    ushort_t* __restrict__ wthi, ushort_t* __restrict__ wtlo,
    ushort_t* __restrict__ wot)
{
    const int id = blockIdx.x * 256 + threadIdx.x;
    if (id < XCH) {
        float f[8];
        *(float4*)&f[0] = *(const float4*)(x + (size_t)id * 8);
        *(float4*)&f[4] = *(const float4*)(x + (size_t)id * 8 + 4);
        bf16x8 hi, lo; cvt8_hilo(f, hi, lo);
        v8cast ch; ch.v = hi; *(uint4*)&xhi[(size_t)id * 8] = ch.u;
        v8cast cl; cl.v = lo; *(uint4*)&xlo[(size_t)id * 8] = cl.u;
    } else if (id < XCH + 3 * WCH) {
        int r = id - XCH;
        const int z = r / WCH; r -= z * WCH;          // WCH is pow2
        const float* __restrict__ W = (z == 0) ? Wq : (z == 1) ? Wk : Wv;
        const int n = r >> 5, kc = (r & 31) * 8;
        float f[8];
        #pragma unroll
        for (int j = 0; j < 8; ++j) f[j] = W[(size_t)(kc + j) * EMBED + n];
        bf16x8 hi, lo; cvt8_hilo(f, hi, lo);
        v8cast ch; ch.v = hi; *(uint4*)&wthi[(size_t)z * WSZ + n * EMBED + kc] = ch.u;
        v8cast cl; cl.v = lo; *(uint4*)&wtlo[(size_t)z * WSZ + n * EMBED + kc] = cl.u;
    } else {
        int r = id - XCH - 3 * WCH;
        const int n = r >> 5, kc = (r & 31) * 8;
        float f[8];
        #pragma unroll
        for (int j = 0; j < 8; ++j) f[j] = Wo[(size_t)(kc + j) * EMBED + n];
        bf16x8 hi, lo; cvt8_hilo(f, hi, lo);
        v8cast ch; ch.v = hi; *(uint4*)&wot[n * EMBED + kc] = ch.u;
    }
}

// ---------------------------------------------------------------------------
// Kernel 1: QKV projection, pure-bf16 MFMA (precomputed hi/lo operands).
// grid (108, 8, 3) x 64 (1 wave).  Wave tile 32(M) x 32(N), K=256.
// Per k-step: 8 x b128 loads + 12 MFMA (3-term hi/lo product, al*bl dropped).
// Q,K -> [b][h][s][p] bf16;  V -> [b][h][p][s] bf16 (transposed).
// ---------------------------------------------------------------------------
__global__ __launch_bounds__(64) void qkv_gemm_kernel(
    const ushort_t* __restrict__ xhi, const ushort_t* __restrict__ xlo,
    const ushort_t* __restrict__ wthi, const ushort_t* __restrict__ wtlo,
    const float* __restrict__ bq, const float* __restrict__ bk, const float* __restrict__ bv,
    ushort_t* __restrict__ qo, ushort_t* __restrict__ ko, ushort_t* __restrict__ vt)
{
    const int lane = threadIdx.x, li = lane & 15, quad = lane >> 4;
    const int m0 = blockIdx.x * 32, n0 = blockIdx.y * 32, z = blockIdx.z;
    const float* __restrict__ bias = (z == 0) ? bq : (z == 1) ? bk : bv;

    const ushort_t* ahp = xhi + (size_t)(m0 + li) * EMBED + quad * 8;
    const ushort_t* alp = xlo + (size_t)(m0 + li) * EMBED + quad * 8;
    const ushort_t* bhp = wthi + (size_t)z * WSZ + (size_t)(n0 + li) * EMBED + quad * 8;
    const ushort_t* blp = wtlo + (size_t)z * WSZ + (size_t)(n0 + li) * EMBED + quad * 8;

    f32x4 acc[2][2];
    #pragma unroll
    for (int mt = 0; mt < 2; ++mt)
        #pragma unroll
        for (int nt = 0; nt < 2; ++nt)
            acc[mt][nt] = (f32x4){0.f, 0.f, 0.f, 0.f};

    #pragma unroll 2
    for (int k0 = 0; k0 < EMBED; k0 += 32) {
        bf16x8 ah[2], al[2], bh[2], bl[2];
        #pragma unroll
        for (int mt = 0; mt < 2; ++mt) {
            ah[mt] = *(const bf16x8*)(ahp + (size_t)mt * 16 * EMBED + k0);
            al[mt] = *(const bf16x8*)(alp + (size_t)mt * 16 * EMBED + k0);
        }
        #pragma unroll
        for (int nt = 0; nt < 2; ++nt) {
            bh[nt] = *(const bf16x8*)(bhp + (size_t)nt * 16 * EMBED + k0);
            bl[nt] = *(const bf16x8*)(blp + (size_t)nt * 16 * EMBED + k0);
        }
        #pragma unroll
        for (int mt = 0; mt < 2; ++mt)
            #pragma unroll
            for (int nt = 0; nt < 2; ++nt) {
                acc[mt][nt] = __builtin_amdgcn_mfma_f32_16x16x32_bf16(ah[mt], bh[nt], acc[mt][nt], 0, 0, 0);
                acc[mt][nt] = __builtin_amdgcn_mfma_f32_16x16x32_bf16(al[mt], bh[nt], acc[mt][nt], 0, 0, 0);
                acc[mt][nt] = __builtin_amdgcn_mfma_f32_16x16x32_bf16(ah[mt], bl[nt], acc[mt][nt], 0, 0, 0);
            }
    }

    const int b = m0 / SEQ;          // 32-row tile never straddles batch (SEQ%32==0)
    const int sbase = m0 - b * SEQ;

    if (z <= 1) {
        ushort_t* __restrict__ dst = z ? ko : qo;
        #pragma unroll
        for (int nt = 0; nt < 2; ++nt) {
            const int gcol = n0 + nt * 16 + li;
            const int h = gcol >> 5, p = gcol & 31;
            const float bb = bias[gcol];
            ushort_t* base = dst + ((size_t)(b * HEADS + h) * SEQ) * PDIM + p;
            #pragma unroll
            for (int mt = 0; mt < 2; ++mt)
                #pragma unroll
                for (int r = 0; r < 4; ++r) {
                    const int s = sbase + mt * 16 + quad * 4 + r;
                    base[(size_t)s * PDIM] = f2bf_rne(acc[mt][nt][r] + bb);
                }
        }
    } else {
        #pragma unroll
        for (int nt = 0; nt < 2; ++nt) {
            const int gcol = n0 + nt * 16 + li;
            const int h = gcol >> 5, p = gcol & 31;
            const float bb = bias[gcol];
            ushort_t* base = vt + ((size_t)(b * HEADS + h) * PDIM + p) * SEQ;
            #pragma unroll
            for (int mt = 0; mt < 2; ++mt) {
                const int s0 = sbase + mt * 16 + quad * 4;
                ushort4 w;
                w.x = f2bf_rne(acc[mt][nt][0] + bb);
                w.y = f2bf_rne(acc[mt][nt][1] + bb);
                w.z = f2bf_rne(acc[mt][nt][2] + bb);
                w.w = f2bf_rne(acc[mt][nt][3] + bb);
                *(ushort4*)&base[s0] = w;
            }
        }
    }
}

// ---------------------------------------------------------------------------
// Kernel 2: flash attention, 8 waves x 64 q-rows per block, KV-parity split.
// grid (27, 16) x 512.  Wave w: q-group qg=w>>1 (16 rows), half=w&1.
// Each iteration stages a PAIR of 64-key tiles (2i, 2i+1) into dbuf LDS;
// half-0 waves consume even tiles, half-1 odd -> serial chain 14 not 27.
// Partial (m,l,O) flash-combined across wave pairs through LDS at the end.
// Output bf16 [b][s][h][p].
// ---------------------------------------------------------------------------
__global__ __launch_bounds__(512, 4) void attn_kernel(
    const ushort_t* __restrict__ q, const ushort_t* __restrict__ k,
    const ushort_t* __restrict__ vt, ushort_t* __restrict__ aob)
{
    const int t    = threadIdx.x;
    const int lane = t & 63;
    const int w    = t >> 6;
    const int li   = lane & 15;
    const int quad = lane >> 4;
    const int qg   = w >> 1, half = w & 1;
    const int bh = blockIdx.y;
    const int b  = bh >> 3, h = bh & 7;
    const int q0 = blockIdx.x * 64 + qg * 16;

    const ushort_t* __restrict__ qb = q  + (size_t)bh * SEQ * PDIM;
    const ushort_t* __restrict__ kb = k  + (size_t)bh * SEQ * PDIM;
    const ushort_t* __restrict__ vb = vt + (size_t)bh * PDIM * SEQ;

    __shared__ ushort_t Ks[2][2][64][40];   // [buf][tile-of-pair][key][p]
    __shared__ ushort_t Vs[2][2][32][72];   // [buf][tile-of-pair][p][key]
    __shared__ ushort_t Ps[8][16][72];      // per-wave P transpose buffer
    __shared__ float    Om[8][16][33];      // per-wave partial O
    __shared__ float    Ml[8][2][16];       // per-wave partial m,l

    const bf16x8 qfrag = *(const bf16x8*)(qb + (size_t)(q0 + li) * PDIM + quad * 8);

    // staging: 512 threads cover 2 K tiles (8 KB) + 2 V tiles (8 KB), 16B each
    const int ktil = t >> 8;                       // wave-uniform: waves 0-3 / 4-7
    const int krow = (t >> 2) & 63, kck = (t & 3) * 8;
    const int vrow = (t >> 3) & 31, vcv = (t & 7) * 8;
    const ushort_t* kgp = kb + (size_t)(ktil * 64 + krow) * PDIM + kck;
    const ushort_t* vgp = vb + (size_t)vrow * SEQ + ktil * 64 + vcv;

    f32x4 o0 = {0.f, 0.f, 0.f, 0.f};
    f32x4 o1 = {0.f, 0.f, 0.f, 0.f};
    float m_run = -__builtin_inff(), l_run = 0.f;

    uint4 kreg = *(const uint4*)(kgp);
    uint4 vreg = *(const uint4*)(vgp);

    #pragma unroll 2
    for (int i = 0; i < NPAIR; ++i) {
        const int p = i & 1;
        *(uint4*)&Ks[p][ktil][krow][kck] = kreg;
        *(uint4*)&Vs[p][ktil][vrow][vcv] = vreg;
        __syncthreads();
        if (i + 1 < NPAIR && 2 * (i + 1) + ktil < NKT) {
            kreg = *(const uint4*)(kgp + (size_t)(2 * (i + 1)) * 64 * PDIM);
            vreg = *(const uint4*)(vgp + 2 * (i + 1) * 64);
        }
        const int kt = 2 * i + half;
        if (kt < NKT) {
            // ---- S^T = K * Q^T ----
            const f32x4 zero = {0.f, 0.f, 0.f, 0.f};
            f32x4 st[4];
            #pragma unroll
            for (int jt = 0; jt < 4; ++jt) {
                const bf16x8 kf = *(const bf16x8*)&Ks[p][half][jt * 16 + li][quad * 8];
                st[jt] = __builtin_amdgcn_mfma_f32_16x16x32_bf16(kf, qfrag, zero, 0, 0, 0);
            }

            // ---- online softmax (per-lane stats for query col i=li) ----
            float tm = fmaxf(fmaxf(fmaxf(st[0][0], st[0][1]), fmaxf(st[0][2], st[0][3])),
                             fmaxf(fmaxf(st[1][0], st[1][1]), fmaxf(st[1][2], st[1][3])));
            tm = fmaxf(tm, fmaxf(fmaxf(fmaxf(st[2][0], st[2][1]), fmaxf(st[2][2], st[2][3])),
                                 fmaxf(fmaxf(st[3][0], st[3][1]), fmaxf(st[3][2], st[3][3]))));
            tm = fmaxf(tm, __shfl_xor(tm, 16));
            tm = fmaxf(tm, __shfl_xor(tm, 32));
            const float mnew  = fmaxf(m_run, tm);
            const float negml = -(mnew * LOG2E);

            float ps = 0.f;
            #pragma unroll
            for (int jt = 0; jt < 4; ++jt) {
                const float p0 = __builtin_amdgcn_exp2f(fmaf(st[jt][0], LOG2E, negml));
                const float p1 = __builtin_amdgcn_exp2f(fmaf(st[jt][1], LOG2E, negml));
                const float p2 = __builtin_amdgcn_exp2f(fmaf(st[jt][2], LOG2E, negml));
                const float p3 = __builtin_amdgcn_exp2f(fmaf(st[jt][3], LOG2E, negml));
                ps += (p0 + p1) + (p2 + p3);
                uint2 pw;
                pw.x = __builtin_amdgcn_perm(__float_as_uint(p1) + 0x8000u,
                                             __float_as_uint(p0) + 0x8000u, 0x07060302u);
                pw.y = __builtin_amdgcn_perm(__float_as_uint(p3) + 0x8000u,
                                             __float_as_uint(p2) + 0x8000u, 0x07060302u);
                *(uint2*)&Ps[w][li][16 * jt + 4 * quad] = pw;
            }
            ps += __shfl_xor(ps, 16);
            ps += __shfl_xor(ps, 32);

            const float alpha = __builtin_amdgcn_exp2f(fmaf(m_run, LOG2E, negml));
            l_run = fmaf(l_run, alpha, ps);
            m_run = mnew;

            float af[4];
            #pragma unroll
            for (int r = 0; r < 4; ++r) af[r] = __shfl(alpha, 4 * quad + r);
            #pragma unroll
            for (int r = 0; r < 4; ++r) { o0[r] *= af[r]; o1[r] *= af[r]; }

            // ---- O += P * V ----
            const bf16x8 pa0 = *(const bf16x8*)&Ps[w][li][8 * quad];
            const bf16x8 pa1 = *(const bf16x8*)&Ps[w][li][32 + 8 * quad];
            const bf16x8 vf00 = *(const bf16x8*)&Vs[p][half][li][quad * 8];
            const bf16x8 vf01 = *(const bf16x8*)&Vs[p][half][16 + li][quad * 8];
            const bf16x8 vf10 = *(const bf16x8*)&Vs[p][half][li][32 + quad * 8];
            const bf16x8 vf11 = *(const bf16x8*)&Vs[p][half][16 + li][32 + quad * 8];
            o0 = __builtin_amdgcn_mfma_f32_16x16x32_bf16(pa0, vf00, o0, 0, 0, 0);
            o0 = __builtin_amdgcn_mfma_f32_16x16x32_bf16(pa1, vf10, o0, 0, 0, 0);
            o1 = __builtin_amdgcn_mfma_f32_16x16x32_bf16(pa0, vf01, o1, 0, 0, 0);
            o1 = __builtin_amdgcn_mfma_f32_16x16x32_bf16(pa1, vf11, o1, 0, 0, 0);
        }
    }

    // ---- publish partials ----
    #pragma unroll
    for (int r = 0; r < 4; ++r) {
        Om[w][4 * quad + r][li]      = o0[r];
        Om[w][4 * quad + r][16 + li] = o1[r];
    }
    if (quad == 0) { Ml[w][0][li] = m_run; Ml[w][1][li] = l_run; }
    __syncthreads();

    // ---- flash combine across the wave pair; each wave writes its 16 cols ----
    const int wa = qg * 2, wb = wa + 1;
    const float ma = Ml[wa][0][li], mb = Ml[wb][0][li];
    const float mC = fmaxf(ma, mb);
    const float sa = __builtin_amdgcn_exp2f((ma - mC) * LOG2E);
    const float sb = __builtin_amdgcn_exp2f((mb - mC) * LOG2E);
    const float lC = Ml[wa][1][li] * sa + Ml[wb][1][li] * sb;
    const float inv = 1.0f / lC;
    const float fa = sa * inv, fb = sb * inv;
    const int c = half * 16 + li;
    #pragma unroll
    for (int r = 0; r < 4; ++r) {
        const int qq = 4 * quad + r;
        const float aq = __shfl(fa, qq);
        const float bq_ = __shfl(fb, qq);
        const float val = Om[wa][qq][c] * aq + Om[wb][qq][c] * bq_;
        const int s = q0 + qq;
        aob[((size_t)(b * SEQ + s)) * EMBED + h * PDIM + c] = f2bf_rne(val);
    }
}

// ---------------------------------------------------------------------------
// Kernel 3: output projection, bf16 MFMA, precomputed Wo^T bf16.
// grid (108, 16) x 64.  Wave tile 32(M) x 16(N), K=256.  out fp32.
// ---------------------------------------------------------------------------
__global__ __launch_bounds__(64) void out_gemm_kernel(
    const ushort_t* __restrict__ a, const ushort_t* __restrict__ wot,
    const float* __restrict__ bo, float* __restrict__ out)
{
    const int lane = threadIdx.x, li = lane & 15, quad = lane >> 4;
    const int m0 = blockIdx.x * 32, n0 = blockIdx.y * 16;

    const ushort_t* ap = a + (size_t)(m0 + li) * EMBED + quad * 8;
    const ushort_t* bp = wot + (size_t)(n0 + li) * EMBED + quad * 8;

    f32x4 acc[2];
    #pragma unroll
    for (int mt = 0; mt < 2; ++mt) acc[mt] = (f32x4){0.f, 0.f, 0.f, 0.f};

    #pragma unroll 2
    for (int k0 = 0; k0 < EMBED; k0 += 32) {
        bf16x8 ah[2];
        #pragma unroll
        for (int mt = 0; mt < 2; ++mt)
            ah[mt] = *(const bf16x8*)(ap + (size_t)mt * 16 * EMBED + k0);
        const bf16x8 bf = *(const bf16x8*)(bp + k0);
        #pragma unroll
        for (int mt = 0; mt < 2; ++mt)
            acc[mt] = __builtin_amdgcn_mfma_f32_16x16x32_bf16(ah[mt], bf, acc[mt], 0, 0, 0);
    }

    const float bb = bo[n0 + li];
    #pragma unroll
    for (int mt = 0; mt < 2; ++mt)
        #pragma unroll
        for (int r = 0; r < 4; ++r) {
            const int row = m0 + mt * 16 + quad * 4 + r;
            out[(size_t)row * EMBED + n0 + li] = acc[mt][r] + bb;
        }
}

// ---------------------------------------------------------------------------
extern "C" void kernel_launch(void* const* d_in, const int* in_sizes, int n_in,
                              void* d_out, int out_size, void* d_ws, size_t ws_size,
                              hipStream_t stream)
{
    const float* x  = (const float*)d_in[0];
    const float* Wq = (const float*)d_in[1];
    const float* bq = (const float*)d_in[2];
    const float* Wk = (const float*)d_in[3];
    const float* bk = (const float*)d_in[4];
    const float* Wv = (const float*)d_in[5];
    const float* bv = (const float*)d_in[6];
    const float* Wo = (const float*)d_in[7];
    const float* bo = (const float*)d_in[8];
    float* out = (float*)d_out;

    ushort_t* ws   = (ushort_t*)d_ws;
    ushort_t* qb   = ws;                         // [b][h][s][p] bf16
    ushort_t* kb   = qb   + (size_t)NE;
    ushort_t* vtb  = kb   + (size_t)NE;          // [b][h][p][s] bf16
    ushort_t* aob  = vtb  + (size_t)NE;          // [b][s][h][p] bf16
    ushort_t* xhi  = aob  + (size_t)NE;          // [tok][k] bf16
    ushort_t* xlo  = xhi  + (size_t)NE;
    ushort_t* wthi = xlo  + (size_t)NE;          // [z][n][k] bf16
    ushort_t* wtlo = wthi + (size_t)(3 * WSZ);
    ushort_t* wot  = wtlo + (size_t)(3 * WSZ);   // [n][k] bf16

    prep_kernel<<<dim3((XCH + 4 * WCH) / 256), 256, 0, stream>>>(
        x, Wq, Wk, Wv, Wo, xhi, xlo, wthi, wtlo, wot);
    qkv_gemm_kernel<<<dim3(NTOK / 32, 8, 3), 64, 0, stream>>>(
        xhi, xlo, wthi, wtlo, bq, bk, bv, qb, kb, vtb);
    attn_kernel<<<dim3(SEQ / 64, BATCH * HEADS), 512, 0, stream>>>(qb, kb, vtb, aob);
    out_gemm_kernel<<<dim3(NTOK / 32, 16), 64, 0, stream>>>(aob, wot, bo, out);
}